// Round 2
// baseline (654.732 us; speedup 1.0000x reference)
//
#include <hip/hip_runtime.h>

#define NN 50000
#define NE 600000

// ---------------------------------------------------------------------------
// Detect whether edge buffer is int64 (odd int32 words all zero) or int32.
__global__ void detect_kernel(const int* __restrict__ ei, int* __restrict__ flag) {
    if (threadIdx.x == 0 && blockIdx.x == 0) {
        *flag = ((ei[1] | ei[3] | ei[5] | ei[7] | ei[9] | ei[11]) == 0) ? 1 : 0;
    }
}

// Canonicalize edges to int32 in workspace (handles int64 or int32 input).
__global__ __launch_bounds__(256) void convert_kernel(const int* __restrict__ ei,
                                                      const int* __restrict__ flag,
                                                      int* __restrict__ e32) {
    int i = blockIdx.x * 256 + threadIdx.x;
    if (i < 2 * NE) {
        e32[i] = (*flag) ? ei[2 * i] : ei[i];
    }
}

// ---------------------------------------------------------------------------
__global__ __launch_bounds__(256) void count_kernel(const int* __restrict__ e32,
                                                    int* __restrict__ cnt) {
    int e = blockIdx.x * 256 + threadIdx.x;
    if (e < NE) atomicAdd(&cnt[e32[NE + e]], 1);
}

// ---------------------------------------------------------------------------
// scatter-add: sums[dst][d] += feat[src][d] for every edge. feat is [NN][D].
template <int D>
__global__ __launch_bounds__(256) void scatter_kernel(const float* __restrict__ feat,
                                                      const int* __restrict__ e32,
                                                      float* __restrict__ sums) {
    int idx = blockIdx.x * 256 + threadIdx.x;   // < NE*D <= 76.8M, fits int
    int e = idx / D;
    int d = idx % D;
    if (e < NE) {
        int s = e32[e];
        int t = e32[NE + e];
        atomicAdd(&sums[t * D + d], feat[s * D + d]);
    }
}

// ---------------------------------------------------------------------------
// Layer 1: out[r][c] = relu( (sum[r]/max(cnt,1)) @ Wl.T + xin @ Wr.T + bias )
// K = 128, N = 128. 32 rows/block, 256 threads; thread: 8 rows x 2 cols.
__global__ __launch_bounds__(256) void lin1_kernel(const float* __restrict__ sum,
                                                   const int* __restrict__ cnt,
                                                   const float* __restrict__ xin,
                                                   const float* __restrict__ Wl,
                                                   const float* __restrict__ Wr,
                                                   const float* __restrict__ bias,
                                                   float* __restrict__ out) {
    constexpr int K = 128, N = 128, KC = 16, NB = 32, NC = 2;
    constexpr int AS = K + 4;     // A row stride (floats), 16B-aligned rows
    constexpr int WS = KC + 4;

    __shared__ float sA[NB * AS];
    __shared__ float sX[NB * AS];
    __shared__ float sWl[N * WS];
    __shared__ float sWr[N * WS];
    __shared__ float sInv[NB];

    const int t = threadIdx.x;
    const int lane = t & 63;
    const int wv = t >> 6;
    const int row0 = blockIdx.x * NB;

    if (t < NB) {
        int r = row0 + t;
        float c = (r < NN) ? (float)cnt[r] : 1.0f;
        sInv[t] = 1.0f / fmaxf(c, 1.0f);
    }
    __syncthreads();

    for (int v = t; v < NB * (K / 4); v += 256) {
        int r = v >> 5;
        int q = v & 31;
        int gr = row0 + r;
        float4 a = make_float4(0.f, 0.f, 0.f, 0.f);
        float4 xx = a;
        if (gr < NN) {
            a  = ((const float4*)sum)[gr * (K / 4) + q];
            xx = ((const float4*)xin)[gr * (K / 4) + q];
        }
        float iv = sInv[r];
        a.x *= iv; a.y *= iv; a.z *= iv; a.w *= iv;
        *(float4*)&sA[r * AS + q * 4] = a;
        *(float4*)&sX[r * AS + q * 4] = xx;
    }

    float acc[8][NC];
#pragma unroll
    for (int i = 0; i < 8; ++i)
#pragma unroll
        for (int j = 0; j < NC; ++j) acc[i][j] = 0.f;

    for (int kc = 0; kc < K; kc += KC) {
        __syncthreads();   // prev chunk consumed (first iter: covers A/X stage)
        for (int v = t; v < N * (KC / 4); v += 256) {
            int c = v >> 2;
            int q = v & 3;
            *(float4*)&sWl[c * WS + q * 4] = ((const float4*)Wl)[c * (K / 4) + (kc >> 2) + q];
            *(float4*)&sWr[c * WS + q * 4] = ((const float4*)Wr)[c * (K / 4) + (kc >> 2) + q];
        }
        __syncthreads();

#pragma unroll
        for (int k4 = 0; k4 < KC; k4 += 4) {
            float4 wl[NC], wr[NC];
#pragma unroll
            for (int j = 0; j < NC; ++j) {
                int c = lane + j * 64;
                wl[j] = *(const float4*)&sWl[c * WS + k4];
                wr[j] = *(const float4*)&sWr[c * WS + k4];
            }
#pragma unroll
            for (int i = 0; i < 8; ++i) {
                int r = wv * 8 + i;
                float4 a  = *(const float4*)&sA[r * AS + kc + k4];
                float4 xx = *(const float4*)&sX[r * AS + kc + k4];
#pragma unroll
                for (int j = 0; j < NC; ++j) {
                    acc[i][j] += a.x * wl[j].x + a.y * wl[j].y +
                                 a.z * wl[j].z + a.w * wl[j].w +
                                 xx.x * wr[j].x + xx.y * wr[j].y +
                                 xx.z * wr[j].z + xx.w * wr[j].w;
                }
            }
        }
    }

#pragma unroll
    for (int i = 0; i < 8; ++i) {
        int r = row0 + wv * 8 + i;
        if (r < NN) {
#pragma unroll
            for (int j = 0; j < NC; ++j) {
                int c = lane + j * 64;
                out[r * N + c] = fmaxf(acc[i][j] + bias[c], 0.f);
            }
        }
    }
}

// ---------------------------------------------------------------------------
// Layer 2 pre-transform (linearity of mean): g = h @ W2l.T, rout = h @ W2r.T
// h is [NN][128]; g, rout are [NN][64]. No bias here.
__global__ __launch_bounds__(256) void lin2_kernel(const float* __restrict__ h,
                                                   const float* __restrict__ Wl,
                                                   const float* __restrict__ Wr,
                                                   float* __restrict__ g,
                                                   float* __restrict__ rout) {
    constexpr int K = 128, KC = 16, NB = 32;
    constexpr int AS = K + 4, WS = KC + 4;

    __shared__ float sH[NB * AS];
    __shared__ float sWl[64 * WS];
    __shared__ float sWr[64 * WS];

    const int t = threadIdx.x;
    const int lane = t & 63;
    const int wv = t >> 6;
    const int row0 = blockIdx.x * NB;

    for (int v = t; v < NB * (K / 4); v += 256) {
        int r = v >> 5;
        int q = v & 31;
        int gr = row0 + r;
        float4 a = make_float4(0.f, 0.f, 0.f, 0.f);
        if (gr < NN) a = ((const float4*)h)[gr * (K / 4) + q];
        *(float4*)&sH[r * AS + q * 4] = a;
    }

    float accL[8], accR[8];
#pragma unroll
    for (int i = 0; i < 8; ++i) { accL[i] = 0.f; accR[i] = 0.f; }

    for (int kc = 0; kc < K; kc += KC) {
        __syncthreads();
        for (int v = t; v < 64 * (KC / 4); v += 256) {   // exactly 1 iter
            int c = v >> 2;
            int q = v & 3;
            *(float4*)&sWl[c * WS + q * 4] = ((const float4*)Wl)[c * (K / 4) + (kc >> 2) + q];
            *(float4*)&sWr[c * WS + q * 4] = ((const float4*)Wr)[c * (K / 4) + (kc >> 2) + q];
        }
        __syncthreads();

#pragma unroll
        for (int k4 = 0; k4 < KC; k4 += 4) {
            float4 wl = *(const float4*)&sWl[lane * WS + k4];
            float4 wr = *(const float4*)&sWr[lane * WS + k4];
#pragma unroll
            for (int i = 0; i < 8; ++i) {
                float4 a = *(const float4*)&sH[(wv * 8 + i) * AS + kc + k4];
                accL[i] += a.x * wl.x + a.y * wl.y + a.z * wl.z + a.w * wl.w;
                accR[i] += a.x * wr.x + a.y * wr.y + a.z * wr.z + a.w * wr.w;
            }
        }
    }

#pragma unroll
    for (int i = 0; i < 8; ++i) {
        int r = row0 + wv * 8 + i;
        if (r < NN) {
            g[r * 64 + lane]    = accL[i];
            rout[r * 64 + lane] = accR[i];
        }
    }
}

// ---------------------------------------------------------------------------
// out[i] += b2[c] + sum2g[i] / max(cnt[r],1)
__global__ __launch_bounds__(256) void finalize_kernel(const float* __restrict__ sum2,
                                                       const int* __restrict__ cnt,
                                                       const float* __restrict__ b2,
                                                       float* __restrict__ out) {
    int i = blockIdx.x * 256 + threadIdx.x;
    if (i < NN * 64) {
        int r = i >> 6;
        int c = i & 63;
        float inv = 1.0f / fmaxf((float)cnt[r], 1.0f);
        out[i] += b2[c] + sum2[i] * inv;
    }
}

// ---------------------------------------------------------------------------
extern "C" void kernel_launch(void* const* d_in, const int* in_sizes, int n_in,
                              void* d_out, int out_size, void* d_ws, size_t ws_size,
                              hipStream_t stream) {
    const float* x   = (const float*)d_in[0];
    const int*   ei  = (const int*)d_in[1];
    const float* W1l = (const float*)d_in[2];
    const float* b1  = (const float*)d_in[3];
    const float* W1r = (const float*)d_in[4];
    const float* W2l = (const float*)d_in[5];
    const float* b2  = (const float*)d_in[6];
    const float* W2r = (const float*)d_in[7];
    float* out = (float*)d_out;

    char* ws = (char*)d_ws;
    int*   flag = (int*)ws;                          // 16 B slot
    int*   e32  = (int*)(ws + 16);                   // 2*NE ints
    int*   cnt  = e32 + 2 * NE;                      // NN ints
    float* sum1 = (float*)(cnt + NN);                // NN*128 floats
    float* h    = sum1 + (size_t)NN * 128;           // NN*128 floats

    size_t needed = 16 + (size_t)(2 * NE + NN) * 4 + (size_t)NN * 256 * 4;
    if (ws_size < needed) return;    // fail loudly (zero output) vs corrupt

    // zero cnt + sum1 (contiguous)
    hipMemsetAsync(cnt, 0, (size_t)NN * (1 + 128) * 4, stream);

    detect_kernel<<<1, 64, 0, stream>>>(ei, flag);
    convert_kernel<<<(2 * NE + 255) / 256, 256, 0, stream>>>(ei, flag, e32);
    count_kernel<<<(NE + 255) / 256, 256, 0, stream>>>(e32, cnt);

    // layer 1: aggregate x (D=128), then fused dual-GEMM + relu -> h
    scatter_kernel<128><<<(NE * 128) / 256, 256, 0, stream>>>(x, e32, sum1);
    lin1_kernel<<<(NN + 31) / 32, 256, 0, stream>>>(sum1, cnt, x, W1l, W1r, b1, h);

    // layer 2: transform first (linearity of mean), aggregate g at D=64
    float* g     = sum1;              // reuse (lin1 is done with sum1)
    float* sum2g = sum1 + (size_t)NN * 64;
    hipMemsetAsync(sum2g, 0, (size_t)NN * 64 * 4, stream);
    lin2_kernel<<<(NN + 31) / 32, 256, 0, stream>>>(h, W2l, W2r, g, out);
    scatter_kernel<64><<<(NE * 64) / 256, 256, 0, stream>>>(g, e32, sum2g);
    finalize_kernel<<<(NN * 64 + 255) / 256, 256, 0, stream>>>(sum2g, cnt, b2, out);
}

// Round 3
// 267.536 us; speedup vs baseline: 2.4473x; 2.4473x over previous
//
#include <hip/hip_runtime.h>

#define NN 50000
#define NE 600000
#define NBLK 196   // ceil(NN/256) for the scan

// ---------------------------------------------------------------------------
// Detect whether edge buffer is int64 (odd int32 words all zero) or int32.
__global__ void detect_kernel(const int* __restrict__ ei, int* __restrict__ flag) {
    if (threadIdx.x == 0 && blockIdx.x == 0) {
        *flag = ((ei[1] | ei[3] | ei[5] | ei[7] | ei[9] | ei[11]) == 0) ? 1 : 0;
    }
}

__global__ __launch_bounds__(256) void convert_kernel(const int* __restrict__ ei,
                                                      const int* __restrict__ flag,
                                                      int* __restrict__ e32) {
    int i = blockIdx.x * 256 + threadIdx.x;
    if (i < 2 * NE) e32[i] = (*flag) ? ei[2 * i] : ei[i];
}

// ---------------------------------------------------------------------------
__global__ __launch_bounds__(256) void count_kernel(const int* __restrict__ e32,
                                                    int* __restrict__ cnt) {
    int e = blockIdx.x * 256 + threadIdx.x;
    if (e < NE) atomicAdd(&cnt[e32[NE + e]], 1);
}

// ---------------------------------------------------------------------------
// 3-phase exclusive scan of cnt[NN] -> rowptr[NN]; cursor := rowptr copy.
__global__ __launch_bounds__(256) void scan1_kernel(const int* __restrict__ cnt,
                                                    int* __restrict__ rowptr,
                                                    int* __restrict__ partials) {
    __shared__ int s[256];
    int t = threadIdx.x;
    int i = blockIdx.x * 256 + t;
    int v = (i < NN) ? cnt[i] : 0;
    s[t] = v;
    __syncthreads();
    for (int off = 1; off < 256; off <<= 1) {
        int u = (t >= off) ? s[t - off] : 0;
        __syncthreads();
        s[t] += u;
        __syncthreads();
    }
    if (i < NN) rowptr[i] = s[t] - v;          // exclusive within block
    if (t == 255) partials[blockIdx.x] = s[255];
}

__global__ __launch_bounds__(256) void scan2_kernel(int* __restrict__ partials) {
    __shared__ int s[256];
    int t = threadIdx.x;
    int v = (t < NBLK) ? partials[t] : 0;
    s[t] = v;
    __syncthreads();
    for (int off = 1; off < 256; off <<= 1) {
        int u = (t >= off) ? s[t - off] : 0;
        __syncthreads();
        s[t] += u;
        __syncthreads();
    }
    if (t < NBLK) partials[t] = s[t] - v;      // exclusive
}

__global__ __launch_bounds__(256) void scan3_kernel(int* __restrict__ rowptr,
                                                    const int* __restrict__ partials,
                                                    int* __restrict__ cursor) {
    int i = blockIdx.x * 256 + threadIdx.x;
    if (i < NN) {
        int v = rowptr[i] + partials[blockIdx.x];
        rowptr[i] = v;
        cursor[i] = v;
    }
}

// ---------------------------------------------------------------------------
__global__ __launch_bounds__(256) void fill_kernel(const int* __restrict__ e32,
                                                   int* __restrict__ cursor,
                                                   int* __restrict__ adj) {
    int e = blockIdx.x * 256 + threadIdx.x;
    if (e < NE) {
        int s = e32[e];
        int d = e32[NE + e];
        int p = atomicAdd(&cursor[d], 1);
        adj[p] = s;
    }
}

// ---------------------------------------------------------------------------
// Gather-mean aggregation: one node per block, blockDim = D.
// FUSE_OUT: out[r][d] += mean + bias[d]  (layer-2 epilogue)
// else:     out[r][d]  = mean
template <int D, bool FUSE_OUT>
__global__ __launch_bounds__(D) void aggregate_kernel(const float* __restrict__ feat,
                                                      const int* __restrict__ adj,
                                                      const int* __restrict__ rowptr,
                                                      const int* __restrict__ cnt,
                                                      const float* __restrict__ bias,
                                                      float* out) {
    int r = blockIdx.x;
    int d = threadIdx.x;
    int beg = rowptr[r];
    int deg = cnt[r];
    float acc = 0.f;
    int j = 0;
    for (; j + 4 <= deg; j += 4) {
        int s0 = adj[beg + j + 0];
        int s1 = adj[beg + j + 1];
        int s2 = adj[beg + j + 2];
        int s3 = adj[beg + j + 3];
        acc += feat[(size_t)s0 * D + d] + feat[(size_t)s1 * D + d] +
               feat[(size_t)s2 * D + d] + feat[(size_t)s3 * D + d];
    }
    for (; j < deg; ++j) acc += feat[(size_t)adj[beg + j] * D + d];
    float mean = acc / fmaxf((float)deg, 1.0f);
    if (FUSE_OUT) out[(size_t)r * D + d] += mean + bias[d];
    else          out[(size_t)r * D + d] = mean;
}

// ---------------------------------------------------------------------------
// Layer 1: out[r][c] = relu( agg[r] @ Wl.T + xin[r] @ Wr.T + bias )
// agg and out may alias (in-place): block stages its rows to LDS first.
__global__ __launch_bounds__(256) void lin1_kernel(const float* agg,
                                                   const float* __restrict__ xin,
                                                   const float* __restrict__ Wl,
                                                   const float* __restrict__ Wr,
                                                   const float* __restrict__ bias,
                                                   float* out) {
    constexpr int K = 128, N = 128, KC = 16, NB = 32, NC = 2;
    constexpr int AS = K + 4;
    constexpr int WS = KC + 4;

    __shared__ float sA[NB * AS];
    __shared__ float sX[NB * AS];
    __shared__ float sWl[N * WS];
    __shared__ float sWr[N * WS];

    const int t = threadIdx.x;
    const int lane = t & 63;
    const int wv = t >> 6;
    const int row0 = blockIdx.x * NB;

    for (int v = t; v < NB * (K / 4); v += 256) {
        int r = v >> 5;
        int q = v & 31;
        int gr = row0 + r;
        float4 a = make_float4(0.f, 0.f, 0.f, 0.f);
        float4 xx = a;
        if (gr < NN) {
            a  = ((const float4*)agg)[gr * (K / 4) + q];
            xx = ((const float4*)xin)[gr * (K / 4) + q];
        }
        *(float4*)&sA[r * AS + q * 4] = a;
        *(float4*)&sX[r * AS + q * 4] = xx;
    }

    float acc[8][NC];
#pragma unroll
    for (int i = 0; i < 8; ++i)
#pragma unroll
        for (int j = 0; j < NC; ++j) acc[i][j] = 0.f;

    for (int kc = 0; kc < K; kc += KC) {
        __syncthreads();   // prev chunk consumed (first iter: covers A/X stage)
        for (int v = t; v < N * (KC / 4); v += 256) {
            int c = v >> 2;
            int q = v & 3;
            *(float4*)&sWl[c * WS + q * 4] = ((const float4*)Wl)[c * (K / 4) + (kc >> 2) + q];
            *(float4*)&sWr[c * WS + q * 4] = ((const float4*)Wr)[c * (K / 4) + (kc >> 2) + q];
        }
        __syncthreads();

#pragma unroll
        for (int k4 = 0; k4 < KC; k4 += 4) {
            float4 wl[NC], wr[NC];
#pragma unroll
            for (int j = 0; j < NC; ++j) {
                int c = lane + j * 64;
                wl[j] = *(const float4*)&sWl[c * WS + k4];
                wr[j] = *(const float4*)&sWr[c * WS + k4];
            }
#pragma unroll
            for (int i = 0; i < 8; ++i) {
                int r = wv * 8 + i;
                float4 a  = *(const float4*)&sA[r * AS + kc + k4];
                float4 xx = *(const float4*)&sX[r * AS + kc + k4];
#pragma unroll
                for (int j = 0; j < NC; ++j) {
                    acc[i][j] += a.x * wl[j].x + a.y * wl[j].y +
                                 a.z * wl[j].z + a.w * wl[j].w +
                                 xx.x * wr[j].x + xx.y * wr[j].y +
                                 xx.z * wr[j].z + xx.w * wr[j].w;
                }
            }
        }
    }

#pragma unroll
    for (int i = 0; i < 8; ++i) {
        int r = row0 + wv * 8 + i;
        if (r < NN) {
#pragma unroll
            for (int j = 0; j < NC; ++j) {
                int c = lane + j * 64;
                out[r * N + c] = fmaxf(acc[i][j] + bias[c], 0.f);
            }
        }
    }
}

// ---------------------------------------------------------------------------
// Layer 2 pre-transform: g = h @ W2l.T, rout = h @ W2r.T  (both [NN][64])
__global__ __launch_bounds__(256) void lin2_kernel(const float* __restrict__ h,
                                                   const float* __restrict__ Wl,
                                                   const float* __restrict__ Wr,
                                                   float* __restrict__ g,
                                                   float* __restrict__ rout) {
    constexpr int K = 128, KC = 16, NB = 32;
    constexpr int AS = K + 4, WS = KC + 4;

    __shared__ float sH[NB * AS];
    __shared__ float sWl[64 * WS];
    __shared__ float sWr[64 * WS];

    const int t = threadIdx.x;
    const int lane = t & 63;
    const int wv = t >> 6;
    const int row0 = blockIdx.x * NB;

    for (int v = t; v < NB * (K / 4); v += 256) {
        int r = v >> 5;
        int q = v & 31;
        int gr = row0 + r;
        float4 a = make_float4(0.f, 0.f, 0.f, 0.f);
        if (gr < NN) a = ((const float4*)h)[gr * (K / 4) + q];
        *(float4*)&sH[r * AS + q * 4] = a;
    }

    float accL[8], accR[8];
#pragma unroll
    for (int i = 0; i < 8; ++i) { accL[i] = 0.f; accR[i] = 0.f; }

    for (int kc = 0; kc < K; kc += KC) {
        __syncthreads();
        for (int v = t; v < 64 * (KC / 4); v += 256) {
            int c = v >> 2;
            int q = v & 3;
            *(float4*)&sWl[c * WS + q * 4] = ((const float4*)Wl)[c * (K / 4) + (kc >> 2) + q];
            *(float4*)&sWr[c * WS + q * 4] = ((const float4*)Wr)[c * (K / 4) + (kc >> 2) + q];
        }
        __syncthreads();

#pragma unroll
        for (int k4 = 0; k4 < KC; k4 += 4) {
            float4 wl = *(const float4*)&sWl[lane * WS + k4];
            float4 wr = *(const float4*)&sWr[lane * WS + k4];
#pragma unroll
            for (int i = 0; i < 8; ++i) {
                float4 a = *(const float4*)&sH[(wv * 8 + i) * AS + kc + k4];
                accL[i] += a.x * wl.x + a.y * wl.y + a.z * wl.z + a.w * wl.w;
                accR[i] += a.x * wr.x + a.y * wr.y + a.z * wr.z + a.w * wr.w;
            }
        }
    }

#pragma unroll
    for (int i = 0; i < 8; ++i) {
        int r = row0 + wv * 8 + i;
        if (r < NN) {
            g[r * 64 + lane]    = accL[i];
            rout[r * 64 + lane] = accR[i];
        }
    }
}

// ---------------------------------------------------------------------------
extern "C" void kernel_launch(void* const* d_in, const int* in_sizes, int n_in,
                              void* d_out, int out_size, void* d_ws, size_t ws_size,
                              hipStream_t stream) {
    const float* x   = (const float*)d_in[0];
    const int*   ei  = (const int*)d_in[1];
    const float* W1l = (const float*)d_in[2];
    const float* b1  = (const float*)d_in[3];
    const float* W1r = (const float*)d_in[4];
    const float* W2l = (const float*)d_in[5];
    const float* b2  = (const float*)d_in[6];
    const float* W2r = (const float*)d_in[7];
    float* out = (float*)d_out;

    char* ws = (char*)d_ws;
    int*   flag    = (int*)ws;                        // 1 int (pad to 64B)
    int*   e32     = (int*)(ws + 64);                 // 2*NE
    int*   cnt     = e32 + 2 * NE;                    // NN
    int*   cursor  = cnt + NN;                        // NN
    int*   rowptr  = cursor + NN;                     // NN
    int*   partials= rowptr + NN;                     // NBLK (+ pad)
    int*   adj     = partials + 256;                  // NE
    float* t1      = (float*)(adj + NE);              // NN*128 (agg1 then h)
    float* g       = t1 + (size_t)NN * 128;           // NN*64

    size_t needed = 64 + (size_t)(2 * NE + 3 * NN + 256 + NE) * 4
                  + (size_t)NN * (128 + 64) * 4;
    if (ws_size < needed) return;    // fail loudly vs corrupt

    // zero cnt + cursor (contiguous, 400 KB)
    hipMemsetAsync(cnt, 0, (size_t)2 * NN * 4, stream);

    detect_kernel<<<1, 64, 0, stream>>>(ei, flag);
    convert_kernel<<<(2 * NE + 255) / 256, 256, 0, stream>>>(ei, flag, e32);
    count_kernel<<<(NE + 255) / 256, 256, 0, stream>>>(e32, cnt);

    // CSR build
    scan1_kernel<<<NBLK, 256, 0, stream>>>(cnt, rowptr, partials);
    scan2_kernel<<<1, 256, 0, stream>>>(partials);
    scan3_kernel<<<NBLK, 256, 0, stream>>>(rowptr, partials, cursor);
    fill_kernel<<<(NE + 255) / 256, 256, 0, stream>>>(e32, cursor, adj);

    // layer 1: gather-mean into t1, then in-place dual-GEMM + relu (t1 -> h)
    aggregate_kernel<128, false><<<NN, 128, 0, stream>>>(x, adj, rowptr, cnt,
                                                         nullptr, t1);
    lin1_kernel<<<(NN + 31) / 32, 256, 0, stream>>>(t1, x, W1l, W1r, b1, t1);

    // layer 2: transform first (linearity of mean), then gather-mean += out
    lin2_kernel<<<(NN + 31) / 32, 256, 0, stream>>>(t1, W2l, W2r, g, out);
    aggregate_kernel<64, true><<<NN, 64, 0, stream>>>(g, adj, rowptr, cnt,
                                                      b2, out);
}

// Round 4
// 192.037 us; speedup vs baseline: 3.4094x; 1.3931x over previous
//
#include <hip/hip_runtime.h>

#define NN 50000
#define NE 600000
#define NBLK 196   // ceil(NN/256) for the scan

typedef __attribute__((ext_vector_type(8))) short bf16x8;
typedef __attribute__((ext_vector_type(4))) float f32x4;

__device__ __forceinline__ unsigned short f2bf(float f) {
    union { float f; unsigned int u; } v; v.f = f;
    unsigned int r = v.u + 0x7FFF + ((v.u >> 16) & 1);   // round-to-nearest-even
    return (unsigned short)(r >> 16);
}
__device__ __forceinline__ float bf2f(unsigned short u) {
    union { unsigned int u; float f; } v; v.u = ((unsigned int)u) << 16;
    return v.f;
}

// ---------------------------------------------------------------------------
// Detect whether edge buffer is int64 (odd int32 words all zero) or int32.
__global__ void detect_kernel(const int* __restrict__ ei, int* __restrict__ flag) {
    if (threadIdx.x == 0 && blockIdx.x == 0) {
        *flag = ((ei[1] | ei[3] | ei[5] | ei[7] | ei[9] | ei[11]) == 0) ? 1 : 0;
    }
}

// ---------------------------------------------------------------------------
__global__ __launch_bounds__(256) void count_kernel(const int* __restrict__ ei,
                                                    const int* __restrict__ flag,
                                                    int* __restrict__ cnt) {
    int e = blockIdx.x * 256 + threadIdx.x;
    if (e < NE) {
        int d = (*flag) ? ei[2 * (NE + e)] : ei[NE + e];
        atomicAdd(&cnt[d], 1);
    }
}

// ---------------------------------------------------------------------------
// 3-phase exclusive scan of cnt[NN] -> rowptr[NN]; cursor := rowptr copy.
__global__ __launch_bounds__(256) void scan1_kernel(const int* __restrict__ cnt,
                                                    int* __restrict__ rowptr,
                                                    int* __restrict__ partials) {
    __shared__ int s[256];
    int t = threadIdx.x;
    int i = blockIdx.x * 256 + t;
    int v = (i < NN) ? cnt[i] : 0;
    s[t] = v;
    __syncthreads();
    for (int off = 1; off < 256; off <<= 1) {
        int u = (t >= off) ? s[t - off] : 0;
        __syncthreads();
        s[t] += u;
        __syncthreads();
    }
    if (i < NN) rowptr[i] = s[t] - v;
    if (t == 255) partials[blockIdx.x] = s[255];
}

__global__ __launch_bounds__(256) void scan2_kernel(int* __restrict__ partials) {
    __shared__ int s[256];
    int t = threadIdx.x;
    int v = (t < NBLK) ? partials[t] : 0;
    s[t] = v;
    __syncthreads();
    for (int off = 1; off < 256; off <<= 1) {
        int u = (t >= off) ? s[t - off] : 0;
        __syncthreads();
        s[t] += u;
        __syncthreads();
    }
    if (t < NBLK) partials[t] = s[t] - v;
}

__global__ __launch_bounds__(256) void scan3_kernel(int* __restrict__ rowptr,
                                                    const int* __restrict__ partials,
                                                    int* __restrict__ cursor) {
    int i = blockIdx.x * 256 + threadIdx.x;
    if (i < NN) {
        int v = rowptr[i] + partials[blockIdx.x];
        rowptr[i] = v;
        cursor[i] = v;
    }
}

// ---------------------------------------------------------------------------
__global__ __launch_bounds__(256) void fill_kernel(const int* __restrict__ ei,
                                                   const int* __restrict__ flag,
                                                   int* __restrict__ cursor,
                                                   int* __restrict__ adj) {
    int e = blockIdx.x * 256 + threadIdx.x;
    if (e < NE) {
        int s, d;
        if (*flag) { s = ei[2 * e]; d = ei[2 * (NE + e)]; }
        else       { s = ei[e];     d = ei[NE + e]; }
        int p = atomicAdd(&cursor[d], 1);
        adj[p] = s;
    }
}

// ---------------------------------------------------------------------------
// x (f32) -> xb (bf16), vectorized
__global__ __launch_bounds__(256) void cvt_x_kernel(const float* __restrict__ x,
                                                    unsigned short* __restrict__ xb) {
    int i = blockIdx.x * 256 + threadIdx.x;   // one float4 per thread
    if (i < NN * 128 / 4) {
        float4 v = ((const float4*)x)[i];
        ushort4 o;
        o.x = f2bf(v.x); o.y = f2bf(v.y); o.z = f2bf(v.z); o.w = f2bf(v.w);
        ((ushort4*)xb)[i] = o;
    }
}

// Wb1[c][k] (128x256 bf16) = k<128 ? W1l[c][k] : W1r[c][k-128]
__global__ __launch_bounds__(256) void cvt_w1_kernel(const float* __restrict__ Wl,
                                                     const float* __restrict__ Wr,
                                                     unsigned short* __restrict__ Wb) {
    int i = blockIdx.x * 256 + threadIdx.x;   // 32768 elems
    if (i < 128 * 256) {
        int c = i >> 8, k = i & 255;
        float v = (k < 128) ? Wl[c * 128 + k] : Wr[c * 128 + (k - 128)];
        Wb[i] = f2bf(v);
    }
}

// Wb2[c][k] (128x128 bf16) = c<64 ? W2l[c][k] : W2r[c-64][k]
__global__ __launch_bounds__(256) void cvt_w2_kernel(const float* __restrict__ Wl,
                                                     const float* __restrict__ Wr,
                                                     unsigned short* __restrict__ Wb) {
    int i = blockIdx.x * 256 + threadIdx.x;   // 16384 elems
    if (i < 128 * 128) {
        int c = i >> 7, k = i & 127;
        float v = (c < 64) ? Wl[c * 128 + k] : Wr[(c - 64) * 128 + k];
        Wb[i] = f2bf(v);
    }
}

// ---------------------------------------------------------------------------
// Gather-mean over bf16 features, f32 accumulate.
// FUSE: o32[r][d] += mean + bias[d]   else: o16[r][d] = bf16(mean)
template <int D, bool FUSE>
__global__ __launch_bounds__(D) void aggregate_kernel(const unsigned short* __restrict__ feat,
                                                      const int* __restrict__ adj,
                                                      const int* __restrict__ rowptr,
                                                      const int* __restrict__ cnt,
                                                      const float* __restrict__ bias,
                                                      unsigned short* __restrict__ o16,
                                                      float* __restrict__ o32) {
    int r = blockIdx.x;
    int d = threadIdx.x;
    int beg = rowptr[r];
    int deg = cnt[r];
    float acc = 0.f;
    int j = 0;
    for (; j + 4 <= deg; j += 4) {
        int s0 = adj[beg + j + 0];
        int s1 = adj[beg + j + 1];
        int s2 = adj[beg + j + 2];
        int s3 = adj[beg + j + 3];
        acc += bf2f(feat[(size_t)s0 * D + d]) + bf2f(feat[(size_t)s1 * D + d]) +
               bf2f(feat[(size_t)s2 * D + d]) + bf2f(feat[(size_t)s3 * D + d]);
    }
    for (; j < deg; ++j) acc += bf2f(feat[(size_t)adj[beg + j] * D + d]);
    float mean = acc / fmaxf((float)deg, 1.0f);
    if (FUSE) o32[(size_t)r * D + d] += mean + bias[d];
    else      o16[(size_t)r * D + d] = f2bf(mean);
}

// ---------------------------------------------------------------------------
// MFMA GEMM: C[M][128] = A[M][K] @ Wb[128][K].T, K = KSTEPS*32.
// KSTEPS==8: A row = concat(Aa[row][0:128], Ab[row][0:128]).
// EPI 1: o16[r][c] = bf16(relu(acc + bias[c]))                      (h)
// EPI 2: c<64 -> o16[r*64+c] = bf16(acc); c>=64 -> o32[r*64+c-64]=acc
// Block: 256 thr = 4 waves in 2x2; wave tile 32 rows x 64 cols.
template <int KSTEPS, int EPI>
__global__ __launch_bounds__(256) void mfma_lin_kernel(const unsigned short* __restrict__ Aa,
                                                       const unsigned short* __restrict__ Ab,
                                                       const unsigned short* __restrict__ Wb,
                                                       const float* __restrict__ bias,
                                                       unsigned short* __restrict__ o16,
                                                       float* __restrict__ o32) {
    constexpr int K = KSTEPS * 32;
    const int t = threadIdx.x;
    const int lane = t & 63;
    const int wv = t >> 6;
    const int wr = wv >> 1, wc = wv & 1;
    const int rowbase = blockIdx.x * 64 + wr * 32;
    const int colbase = wc * 64;
    const int l16 = lane & 15;
    const int khi = lane >> 4;        // 0..3

    f32x4 acc[2][4] = {};

#pragma unroll
    for (int ks = 0; ks < KSTEPS; ++ks) {
        const int k0 = ks * 32 + khi * 8;
        bf16x8 a[2];
#pragma unroll
        for (int rt = 0; rt < 2; ++rt) {
            int r = rowbase + rt * 16 + l16;
            r = (r < NN) ? r : (NN - 1);          // clamp; stores are guarded
            const unsigned short* src;
            int kk;
            if (KSTEPS == 8 && ks >= 4) { src = Ab; kk = k0 - 128; }
            else                        { src = Aa; kk = k0; }
            a[rt] = *(const bf16x8*)(src + (size_t)r * 128 + kk);
        }
        bf16x8 b[4];
#pragma unroll
        for (int ct = 0; ct < 4; ++ct) {
            int c = colbase + ct * 16 + l16;
            b[ct] = *(const bf16x8*)(Wb + (size_t)c * K + ks * 32 + khi * 8);
        }
#pragma unroll
        for (int rt = 0; rt < 2; ++rt)
#pragma unroll
            for (int ct = 0; ct < 4; ++ct)
                acc[rt][ct] = __builtin_amdgcn_mfma_f32_16x16x32_bf16(
                    a[rt], b[ct], acc[rt][ct], 0, 0, 0);
    }

#pragma unroll
    for (int rt = 0; rt < 2; ++rt) {
#pragma unroll
        for (int j = 0; j < 4; ++j) {
            int r = rowbase + rt * 16 + khi * 4 + j;
            if (r < NN) {
#pragma unroll
                for (int ct = 0; ct < 4; ++ct) {
                    int c = colbase + ct * 16 + l16;
                    float v = acc[rt][ct][j];
                    if (EPI == 1) {
                        v = fmaxf(v + bias[c], 0.f);
                        o16[(size_t)r * 128 + c] = f2bf(v);
                    } else {
                        if (c < 64) o16[(size_t)r * 64 + c] = f2bf(v);
                        else        o32[(size_t)r * 64 + (c - 64)] = v;
                    }
                }
            }
        }
    }
}

// ---------------------------------------------------------------------------
extern "C" void kernel_launch(void* const* d_in, const int* in_sizes, int n_in,
                              void* d_out, int out_size, void* d_ws, size_t ws_size,
                              hipStream_t stream) {
    const float* x   = (const float*)d_in[0];
    const int*   ei  = (const int*)d_in[1];
    const float* W1l = (const float*)d_in[2];
    const float* b1  = (const float*)d_in[3];
    const float* W1r = (const float*)d_in[4];
    const float* W2l = (const float*)d_in[5];
    const float* b2  = (const float*)d_in[6];
    const float* W2r = (const float*)d_in[7];
    float* out = (float*)d_out;

    char* ws = (char*)d_ws;
    int* flag     = (int*)ws;                          // 64 B slot
    int* cnt      = (int*)(ws + 64);                   // NN
    int* cursor   = cnt + NN;                          // NN
    int* rowptr   = cursor + NN;                       // NN
    int* partials = rowptr + NN;                       // 256
    int* adj      = partials + 256;                    // NE
    unsigned short* xb  = (unsigned short*)(adj + NE); // NN*128
    unsigned short* hb  = xb + (size_t)NN * 128;       // NN*128
    unsigned short* t1b = hb + (size_t)NN * 128;       // NN*128 (agg1), then gb
    unsigned short* gb  = t1b;                         // NN*64 (aliases t1b)
    unsigned short* Wb1 = t1b + (size_t)NN * 128;      // 128*256
    unsigned short* Wb2 = Wb1 + 128 * 256;             // 128*128

    size_t needed = 64 + (size_t)(3 * NN + 256 + NE) * 4
                  + ((size_t)NN * 128 * 3 + 128 * 256 + 128 * 128) * 2;
    if (ws_size < needed) return;    // fail loudly vs corrupt

    hipMemsetAsync(cnt, 0, (size_t)2 * NN * 4, stream);   // cnt + cursor

    detect_kernel<<<1, 64, 0, stream>>>(ei, flag);
    count_kernel<<<(NE + 255) / 256, 256, 0, stream>>>(ei, flag, cnt);

    // CSR build
    scan1_kernel<<<NBLK, 256, 0, stream>>>(cnt, rowptr, partials);
    scan2_kernel<<<1, 256, 0, stream>>>(partials);
    scan3_kernel<<<NBLK, 256, 0, stream>>>(rowptr, partials, cursor);
    fill_kernel<<<(NE + 255) / 256, 256, 0, stream>>>(ei, flag, cursor, adj);

    // bf16 conversions
    cvt_x_kernel<<<(NN * 128 / 4 + 255) / 256, 256, 0, stream>>>(x, xb);
    cvt_w1_kernel<<<(128 * 256 + 255) / 256, 256, 0, stream>>>(W1l, W1r, Wb1);
    cvt_w2_kernel<<<(128 * 128 + 255) / 256, 256, 0, stream>>>(W2l, W2r, Wb2);

    // layer 1: gather-mean(xb) -> t1b; h = relu([t1b|xb] @ Wb1.T + b1) -> hb
    aggregate_kernel<128, false><<<NN, 128, 0, stream>>>(xb, adj, rowptr, cnt,
                                                         nullptr, t1b, nullptr);
    mfma_lin_kernel<8, 1><<<(NN + 63) / 64, 256, 0, stream>>>(t1b, xb, Wb1, b1,
                                                              hb, nullptr);

    // layer 2: [g|rout] = hb @ Wb2.T ; out = rout ; out += mean(g) + b2
    mfma_lin_kernel<4, 2><<<(NN + 63) / 64, 256, 0, stream>>>(hb, nullptr, Wb2,
                                                              nullptr, gb, out);
    aggregate_kernel<64, true><<<NN, 64, 0, stream>>>(gb, adj, rowptr, cnt,
                                                      b2, nullptr, out);
}

// Round 5
// 176.703 us; speedup vs baseline: 3.7053x; 1.0868x over previous
//
#include <hip/hip_runtime.h>

#define NN 50000
#define NE 600000
#define NBLK 196   // ceil(NN/256) for the scan

typedef __attribute__((ext_vector_type(8))) short bf16x8;
typedef __attribute__((ext_vector_type(4))) float f32x4;

__device__ __forceinline__ unsigned short f2bf(float f) {
    union { float f; unsigned int u; } v; v.f = f;
    unsigned int r = v.u + 0x7FFF + ((v.u >> 16) & 1);   // round-to-nearest-even
    return (unsigned short)(r >> 16);
}
__device__ __forceinline__ float bf2f(unsigned short u) {
    union { unsigned int u; float f; } v; v.u = ((unsigned int)u) << 16;
    return v.f;
}

// int64-vs-int32 edge buffer signature (wave-uniform, 6 cached loads)
__device__ __forceinline__ int edges_is64(const int* __restrict__ ei) {
    return ((ei[1] | ei[3] | ei[5] | ei[7] | ei[9] | ei[11]) == 0) ? 1 : 0;
}

// ---------------------------------------------------------------------------
__global__ __launch_bounds__(256) void zero_kernel(int* __restrict__ p) {
    int i = blockIdx.x * 256 + threadIdx.x;
    if (i < NN) p[i] = 0;
}

// ---------------------------------------------------------------------------
__global__ __launch_bounds__(256) void count_kernel(const int* __restrict__ ei,
                                                    int* __restrict__ cnt) {
    int is64 = edges_is64(ei);
    int e = blockIdx.x * 256 + threadIdx.x;
    if (e < NE) {
        int d = is64 ? ei[2 * (NE + e)] : ei[NE + e];
        atomicAdd(&cnt[d], 1);
    }
}

// ---------------------------------------------------------------------------
// 3-phase exclusive scan of cnt[NN] -> rowptr[NN]; cursor := rowptr copy.
__global__ __launch_bounds__(256) void scan1_kernel(const int* __restrict__ cnt,
                                                    int* __restrict__ rowptr,
                                                    int* __restrict__ partials) {
    __shared__ int s[256];
    int t = threadIdx.x;
    int i = blockIdx.x * 256 + t;
    int v = (i < NN) ? cnt[i] : 0;
    s[t] = v;
    __syncthreads();
    for (int off = 1; off < 256; off <<= 1) {
        int u = (t >= off) ? s[t - off] : 0;
        __syncthreads();
        s[t] += u;
        __syncthreads();
    }
    if (i < NN) rowptr[i] = s[t] - v;
    if (t == 255) partials[blockIdx.x] = s[255];
}

__global__ __launch_bounds__(256) void scan2_kernel(int* __restrict__ partials) {
    __shared__ int s[256];
    int t = threadIdx.x;
    int v = (t < NBLK) ? partials[t] : 0;
    s[t] = v;
    __syncthreads();
    for (int off = 1; off < 256; off <<= 1) {
        int u = (t >= off) ? s[t - off] : 0;
        __syncthreads();
        s[t] += u;
        __syncthreads();
    }
    if (t < NBLK) partials[t] = s[t] - v;
}

__global__ __launch_bounds__(256) void scan3_kernel(int* __restrict__ rowptr,
                                                    const int* __restrict__ partials,
                                                    int* __restrict__ cursor) {
    int i = blockIdx.x * 256 + threadIdx.x;
    if (i < NN) {
        int v = rowptr[i] + partials[blockIdx.x];
        rowptr[i] = v;
        cursor[i] = v;
    }
}

// ---------------------------------------------------------------------------
__global__ __launch_bounds__(256) void fill_kernel(const int* __restrict__ ei,
                                                   int* __restrict__ cursor,
                                                   int* __restrict__ adj) {
    int is64 = edges_is64(ei);
    int e = blockIdx.x * 256 + threadIdx.x;
    if (e < NE) {
        int s, d;
        if (is64) { s = ei[2 * e]; d = ei[2 * (NE + e)]; }
        else      { s = ei[e];     d = ei[NE + e]; }
        int p = atomicAdd(&cursor[d], 1);
        adj[p] = s;
    }
}

// ---------------------------------------------------------------------------
// One fused conversion kernel: x -> xb, [W1l|W1r] -> Wb1, [W2l;W2r] -> Wb2.
#define XV   (NN * 128 / 4)          // 1,600,000 float4s
#define W1V  (128 * 256 / 4)         // 8192
#define W2V  (128 * 128 / 4)         // 4096
__global__ __launch_bounds__(256) void cvt_all_kernel(const float* __restrict__ x,
                                                      const float* __restrict__ W1l,
                                                      const float* __restrict__ W1r,
                                                      const float* __restrict__ W2l,
                                                      const float* __restrict__ W2r,
                                                      unsigned short* __restrict__ xb,
                                                      unsigned short* __restrict__ Wb1,
                                                      unsigned short* __restrict__ Wb2) {
    int i = blockIdx.x * 256 + threadIdx.x;
    const float* src = nullptr;
    unsigned short* dst = nullptr;
    if (i < XV) {
        src = x + (size_t)i * 4;
        dst = xb + (size_t)i * 4;
    } else if (i < XV + W1V) {
        int j = (i - XV) * 4;              // elem index in Wb1 [128][256]
        int c = j >> 8, k = j & 255;
        src = (k < 128) ? (W1l + c * 128 + k) : (W1r + c * 128 + (k - 128));
        dst = Wb1 + j;
    } else if (i < XV + W1V + W2V) {
        int j = (i - XV - W1V) * 4;        // elem index in Wb2 [128][128]
        int c = j >> 7, k = j & 127;
        src = (c < 64) ? (W2l + c * 128 + k) : (W2r + (c - 64) * 128 + k);
        dst = Wb2 + j;
    } else {
        return;
    }
    float4 v = *(const float4*)src;
    ushort4 o;
    o.x = f2bf(v.x); o.y = f2bf(v.y); o.z = f2bf(v.z); o.w = f2bf(v.w);
    *(ushort4*)dst = o;
}

// ---------------------------------------------------------------------------
// Gather-mean over bf16 features, f32 accumulate, ushort2 per lane.
// D=128: 64 lanes/node (1 wave = 1 node).  D=64: 32 lanes/node (2 nodes/wave).
// FUSE: o32[node][d] += mean + bias[d]   else: o16[node][d] = bf16(mean)
template <int D, bool FUSE>
__global__ __launch_bounds__(256) void aggregate_kernel(const unsigned short* __restrict__ feat,
                                                        const int* __restrict__ adj,
                                                        const int* __restrict__ rowptr,
                                                        const int* __restrict__ cnt,
                                                        const float* __restrict__ bias,
                                                        unsigned short* __restrict__ o16,
                                                        float* __restrict__ o32) {
    constexpr int LPN = D / 2;           // lanes per node
    constexpr int NPB = 256 / LPN;       // nodes per block
    int node = blockIdx.x * NPB + (threadIdx.x / LPN);
    int l = threadIdx.x & (LPN - 1);
    if (node >= NN) return;
    int beg = rowptr[node];
    int deg = cnt[node];
    const ushort2* fb = (const ushort2*)feat;
    float ax = 0.f, ay = 0.f;
    int j = 0;
    for (; j + 4 <= deg; j += 4) {
        int s0 = adj[beg + j + 0];
        int s1 = adj[beg + j + 1];
        int s2 = adj[beg + j + 2];
        int s3 = adj[beg + j + 3];
        ushort2 v0 = fb[(size_t)s0 * LPN + l];
        ushort2 v1 = fb[(size_t)s1 * LPN + l];
        ushort2 v2 = fb[(size_t)s2 * LPN + l];
        ushort2 v3 = fb[(size_t)s3 * LPN + l];
        ax += bf2f(v0.x) + bf2f(v1.x) + bf2f(v2.x) + bf2f(v3.x);
        ay += bf2f(v0.y) + bf2f(v1.y) + bf2f(v2.y) + bf2f(v3.y);
    }
    for (; j < deg; ++j) {
        ushort2 v = fb[(size_t)adj[beg + j] * LPN + l];
        ax += bf2f(v.x);
        ay += bf2f(v.y);
    }
    float inv = 1.0f / fmaxf((float)deg, 1.0f);
    ax *= inv; ay *= inv;
    if (FUSE) {
        float2* op = (float2*)(o32 + (size_t)node * D + 2 * l);
        float2 cur = *op;
        cur.x += ax + bias[2 * l];
        cur.y += ay + bias[2 * l + 1];
        *op = cur;
    } else {
        ushort2 o;
        o.x = f2bf(ax); o.y = f2bf(ay);
        ((ushort2*)o16)[(size_t)node * LPN + l] = o;
    }
}

// ---------------------------------------------------------------------------
// MFMA GEMM: C[M][128] = A[M][K] @ Wb[128][K].T, K = KSTEPS*32.
// KSTEPS==8: A row = concat(Aa[row][0:128], Ab[row][0:128]).
// EPI 1: o16[r][c] = bf16(relu(acc + bias[c]))                      (h)
// EPI 2: c<64 -> o16[r*64+c] = bf16(acc); c>=64 -> o32[r*64+c-64]=acc
// Block: 256 thr = 4 waves in 2x2; wave tile 32 rows x 64 cols.
template <int KSTEPS, int EPI>
__global__ __launch_bounds__(256) void mfma_lin_kernel(const unsigned short* __restrict__ Aa,
                                                       const unsigned short* __restrict__ Ab,
                                                       const unsigned short* __restrict__ Wb,
                                                       const float* __restrict__ bias,
                                                       unsigned short* __restrict__ o16,
                                                       float* __restrict__ o32) {
    constexpr int K = KSTEPS * 32;
    const int t = threadIdx.x;
    const int lane = t & 63;
    const int wv = t >> 6;
    const int wr = wv >> 1, wc = wv & 1;
    const int rowbase = blockIdx.x * 64 + wr * 32;
    const int colbase = wc * 64;
    const int l16 = lane & 15;
    const int khi = lane >> 4;        // 0..3

    f32x4 acc[2][4] = {};

#pragma unroll
    for (int ks = 0; ks < KSTEPS; ++ks) {
        const int k0 = ks * 32 + khi * 8;
        bf16x8 a[2];
#pragma unroll
        for (int rt = 0; rt < 2; ++rt) {
            int r = rowbase + rt * 16 + l16;
            r = (r < NN) ? r : (NN - 1);          // clamp; stores are guarded
            const unsigned short* src;
            int kk;
            if (KSTEPS == 8 && ks >= 4) { src = Ab; kk = k0 - 128; }
            else                        { src = Aa; kk = k0; }
            a[rt] = *(const bf16x8*)(src + (size_t)r * 128 + kk);
        }
        bf16x8 b[4];
#pragma unroll
        for (int ct = 0; ct < 4; ++ct) {
            int c = colbase + ct * 16 + l16;
            b[ct] = *(const bf16x8*)(Wb + (size_t)c * K + ks * 32 + khi * 8);
        }
#pragma unroll
        for (int rt = 0; rt < 2; ++rt)
#pragma unroll
            for (int ct = 0; ct < 4; ++ct)
                acc[rt][ct] = __builtin_amdgcn_mfma_f32_16x16x32_bf16(
                    a[rt], b[ct], acc[rt][ct], 0, 0, 0);
    }

#pragma unroll
    for (int rt = 0; rt < 2; ++rt) {
#pragma unroll
        for (int j = 0; j < 4; ++j) {
            int r = rowbase + rt * 16 + khi * 4 + j;
            if (r < NN) {
#pragma unroll
                for (int ct = 0; ct < 4; ++ct) {
                    int c = colbase + ct * 16 + l16;
                    float v = acc[rt][ct][j];
                    if (EPI == 1) {
                        v = fmaxf(v + bias[c], 0.f);
                        o16[(size_t)r * 128 + c] = f2bf(v);
                    } else {
                        if (c < 64) o16[(size_t)r * 64 + c] = f2bf(v);
                        else        o32[(size_t)r * 64 + (c - 64)] = v;
                    }
                }
            }
        }
    }
}

// ---------------------------------------------------------------------------
extern "C" void kernel_launch(void* const* d_in, const int* in_sizes, int n_in,
                              void* d_out, int out_size, void* d_ws, size_t ws_size,
                              hipStream_t stream) {
    const float* x   = (const float*)d_in[0];
    const int*   ei  = (const int*)d_in[1];
    const float* W1l = (const float*)d_in[2];
    const float* b1  = (const float*)d_in[3];
    const float* W1r = (const float*)d_in[4];
    const float* W2l = (const float*)d_in[5];
    const float* b2  = (const float*)d_in[6];
    const float* W2r = (const float*)d_in[7];
    float* out = (float*)d_out;

    char* ws = (char*)d_ws;
    int* cnt      = (int*)(ws + 64);                   // NN
    int* cursor   = cnt + NN;                          // NN (scan3-initialized)
    int* rowptr   = cursor + NN;                       // NN
    int* partials = rowptr + NN;                       // 256
    int* adj      = partials + 256;                    // NE
    unsigned short* xb  = (unsigned short*)(adj + NE); // NN*128
    unsigned short* hb  = xb + (size_t)NN * 128;       // NN*128
    unsigned short* t1b = hb + (size_t)NN * 128;       // NN*128 (agg1), then gb
    unsigned short* gb  = t1b;                         // NN*64 (aliases t1b)
    unsigned short* Wb1 = t1b + (size_t)NN * 128;      // 128*256
    unsigned short* Wb2 = Wb1 + 128 * 256;             // 128*128

    size_t needed = 64 + (size_t)(3 * NN + 256 + NE) * 4
                  + ((size_t)NN * 128 * 3 + 128 * 256 + 128 * 128) * 2;
    if (ws_size < needed) return;    // fail loudly vs corrupt

    zero_kernel<<<NBLK, 256, 0, stream>>>(cnt);
    count_kernel<<<(NE + 255) / 256, 256, 0, stream>>>(ei, cnt);

    // CSR build
    scan1_kernel<<<NBLK, 256, 0, stream>>>(cnt, rowptr, partials);
    scan2_kernel<<<1, 256, 0, stream>>>(partials);
    scan3_kernel<<<NBLK, 256, 0, stream>>>(rowptr, partials, cursor);
    fill_kernel<<<(NE + 255) / 256, 256, 0, stream>>>(ei, cursor, adj);

    // bf16 conversions (x, W1, W2) in one kernel
    cvt_all_kernel<<<(XV + W1V + W2V + 255) / 256, 256, 0, stream>>>(
        x, W1l, W1r, W2l, W2r, xb, Wb1, Wb2);

    // layer 1: gather-mean(xb) -> t1b; h = relu([t1b|xb] @ Wb1.T + b1) -> hb
    aggregate_kernel<128, false><<<(NN + 3) / 4, 256, 0, stream>>>(
        xb, adj, rowptr, cnt, nullptr, t1b, nullptr);
    mfma_lin_kernel<8, 1><<<(NN + 63) / 64, 256, 0, stream>>>(t1b, xb, Wb1, b1,
                                                              hb, nullptr);

    // layer 2: [g|rout] = hb @ Wb2.T ; out = rout ; out += mean(g) + b2
    mfma_lin_kernel<4, 2><<<(NN + 63) / 64, 256, 0, stream>>>(hb, nullptr, Wb2,
                                                              nullptr, gb, out);
    aggregate_kernel<64, true><<<(NN + 7) / 8, 256, 0, stream>>>(
        gb, adj, rowptr, cnt, b2, nullptr, out);
}